// Round 3
// baseline (620.478 us; speedup 1.0000x reference)
//
#include <hip/hip_runtime.h>

// TinyLSTM: I=128, H=64, C=10, B=256, T=1024
// R10: fold the producer INTO the consumers' latency shadows; delete the
// producer waves. R9 post-mortem: step = 719 cyc, of which ~250 is the cost
// of wave-specialization itself (8-wave barrier straggle + producer's
// 184-cyc slot-0 burst on shared SIMDs). Per step each wave has a ~120-cyc
// dead window waiting on its h ds_read; one kstep of tile k+1's xproj
// (2 ds_read + 4 cvt + 4 MFMA ~ 50 cyc issue) fits inside it. So: 256 thr,
// 4 SYMMETRIC waves; per step each wave does
//   [h-frag reads][xb reads][tt==0: gll x_{k+2}] -> 8 recurrence MFMA
//   (g-gate first) -> 4 xproj MFMA (tile k+1, kstep tt; P-write at tt==3)
//   -> seed prefetch -> activation -> h write -> lgkm-only barrier.
// lgkm retires in order, so compiler's fine-grained lgkmcnt still releases
// hb0 before the xb/xa reads. vmcnt(0) once per tile on ~3-step-old glls
// (~0 stall). Sync ledger identical to R9 (every cross-wave edge separated
// by >=1 barrier); xproj accumulation order unchanged -> bit-identical.
// LDS: XS 16K + P 34.3K + H2 1.3K = 52K.

#define NI 128
#define NH 64
#define NB 256
#define NT 1024
#define NC 10

#define TT 4
#define NTILE (NT / TT)

#define LOG2E    1.44269504f
#define TWOLOG2E 2.88539008f

typedef __fp16 half2v __attribute__((ext_vector_type(2)));
typedef __fp16 f16x8  __attribute__((ext_vector_type(8)));
typedef float  f32x4  __attribute__((ext_vector_type(4)));

#define HP  80           // H row stride (halves): 160 B, max 2-way banks
#define XPB 268          // xproj batch stride (floats)
#define XPT (4 * XPB)    // xproj timestep stride (floats)

#define MF(acc, a, b) \
    acc = __builtin_amdgcn_mfma_f32_16x16x32_f16(a, b, acc, 0, 0, 0)

__device__ __forceinline__ void block_sync_lds() {
    asm volatile("s_waitcnt lgkmcnt(0)\n\ts_barrier" ::: "memory");
}
__device__ __forceinline__ void wave_drain_vm() {
    asm volatile("s_waitcnt vmcnt(0)" ::: "memory");
}
__device__ __forceinline__ float fast_exp2(float x) {
#if __has_builtin(__builtin_amdgcn_exp2f)
    return __builtin_amdgcn_exp2f(x);
#else
    return __exp2f(x);
#endif
}
__device__ __forceinline__ float fast_rcp(float x) {
    return __builtin_amdgcn_rcpf(x);
}
__device__ __forceinline__ f16x8 pack8(float4 a, float4 b, float s) {
    half2v p0 = __builtin_amdgcn_cvt_pkrtz(a.x * s, a.y * s);
    half2v p1 = __builtin_amdgcn_cvt_pkrtz(a.z * s, a.w * s);
    half2v p2 = __builtin_amdgcn_cvt_pkrtz(b.x * s, b.y * s);
    half2v p3 = __builtin_amdgcn_cvt_pkrtz(b.z * s, b.w * s);
    f16x8 r;
    r[0]=p0[0]; r[1]=p0[1]; r[2]=p1[0]; r[3]=p1[1];
    r[4]=p2[0]; r[5]=p2[1]; r[6]=p3[0]; r[7]=p3[1];
    return r;
}
__device__ __forceinline__ f16x8 pack8n(float4 a, float4 b) {
    half2v p0 = __builtin_amdgcn_cvt_pkrtz(a.x, a.y);
    half2v p1 = __builtin_amdgcn_cvt_pkrtz(a.z, a.w);
    half2v p2 = __builtin_amdgcn_cvt_pkrtz(b.x, b.y);
    half2v p3 = __builtin_amdgcn_cvt_pkrtz(b.z, b.w);
    f16x8 r;
    r[0]=p0[0]; r[1]=p0[1]; r[2]=p1[0]; r[3]=p1[1];
    r[4]=p2[0]; r[5]=p2[1]; r[6]=p3[0]; r[7]=p3[1];
    return r;
}
__device__ __forceinline__ void gload_lds16(const void* g, void* l) {
    __builtin_amdgcn_global_load_lds(
        (const __attribute__((address_space(1))) unsigned int*)g,
        (__attribute__((address_space(3))) unsigned int*)l, 16, 0, 0);
}

__global__ __launch_bounds__(256, 1)
void lstm_one(const float* __restrict__ x,
              const float* __restrict__ W_ih,
              const float* __restrict__ W_hh,
              const float* __restrict__ b_ih,
              const float* __restrict__ b_hh,
              const float* __restrict__ W_cls,
              const float* __restrict__ b_cls,
              float* __restrict__ out) {
    const int tid  = threadIdx.x;
    const int w    = tid >> 6;     // wave: gate rows 64i+16w+col, batch w stage
    const int lane = tid & 63;
    const int col  = lane & 15;    // MFMA n-column
    const int quad = lane >> 4;
    const int bb   = blockIdx.x;   // batches [4bb, 4bb+4)
    const int bcol = col & 3;      // batch within group
    const int cr   = col >> 2;     // recurrence: C-row select / xproj timestep

    __shared__ __align__(16) float  XS[2][4][TT * NI];  // raw x, dbl-buf 16K
    __shared__ __align__(16) float  P[2][TT * XPT];     // xproj f32, dbl 34.3K
    __shared__ __align__(16) __fp16 H2[2][4][HP];       // h f16, dbl-buf 1.3K

    // stage batch (4bb+w) tile -> XS[tile&1][w]. LDS dest linear; src addr
    // ^xo, xo=((row^(row>>1))&7)<<4, row=(w*2048+lin)>>9. Involutive,
    // within-128B-line: coalescing unchanged, produce reads 2-way max.
    auto stage_x = [&](int tile) {
        const char* xsrc = (const char*)(x + ((size_t)(4 * bb + w) * NT
                                              + (size_t)tile * TT) * NI);
        #pragma unroll
        for (int j = 0; j < 2; ++j) {
            const unsigned lin = j * 1024u + (unsigned)lane * 16u;
            const unsigned row = ((unsigned)w * 2048u + lin) >> 9;
            const unsigned xo  = ((row ^ (row >> 1)) & 7u) << 4;
            gload_lds16(xsrc + (lin ^ xo),
                        (char*)&XS[tile & 1][w][0] + j * 1024);
        }
    };
    stage_x(0);
    stage_x(1);

    // ---- weights as MFMA A-frags ----
    f16x8 afrX[4][4];   // W_ih, K=128 (4 ksteps)
    f16x8 afrH[4][2];   // W_hh, K=64  (2 ksteps)
    f32x4 biasf[4];     // prescaled bias in C layout
    #pragma unroll
    for (int i = 0; i < 4; ++i) {
        const int grow = 64 * i + 16 * w + col;
        const float s = (i == 2) ? TWOLOG2E : LOG2E;
        const float* Wx = W_ih + (size_t)grow * NI;
        #pragma unroll
        for (int ks = 0; ks < 4; ++ks) {
            float4 a4 = *(const float4*)(Wx + ks * 32 + quad * 8);
            float4 b4 = *(const float4*)(Wx + ks * 32 + quad * 8 + 4);
            afrX[i][ks] = pack8(a4, b4, s);
        }
        const float* Wh = W_hh + (size_t)grow * NH;
        #pragma unroll
        for (int ks = 0; ks < 2; ++ks) {
            float4 a4 = *(const float4*)(Wh + ks * 32 + quad * 8);
            float4 b4 = *(const float4*)(Wh + ks * 32 + quad * 8 + 4);
            afrH[i][ks] = pack8(a4, b4, s);
        }
        #pragma unroll
        for (int r = 0; r < 4; ++r) {
            const int u = 64 * i + 16 * w + 4 * quad + r;
            biasf[i][r] = (b_ih[u] + b_hh[u]) * s;
        }
    }
    for (int z = tid; z < 2 * 4 * HP / 2; z += 256)
        ((unsigned*)H2)[z] = 0u;        // zero both H bufs

    // per-lane xproj addressing constants (timestep tl = cr, batch bcol)
    const unsigned rowP = (unsigned)(bcol * 4 + cr);
    const unsigned xoP  = ((rowP ^ (rowP >> 1)) & 7u) << 4;
    const unsigned rbP  = rowP * 512u + (unsigned)quad * 32u;

    wave_drain_vm();        // own gll for tiles 0,1 (+ weight loads) landed
    block_sync_lds();       // [A] all waves' stages visible; H2 zeros visible

    // ---- prologue: produce xproj tile 0 (full burst, once) ----
    {
        const char* XSb = (const char*)&XS[0][0][0];
        f16x8 xb[4];
        #pragma unroll
        for (int ks = 0; ks < 4; ++ks) {
            const unsigned l0 = rbP + ks * 128u;
            float4 p0 = *(const float4*)(XSb + (l0 ^ xoP));
            float4 p1 = *(const float4*)(XSb + ((l0 + 16u) ^ xoP));
            xb[ks] = pack8n(p0, p1);
        }
        f32x4 c0 = biasf[0], c1 = biasf[1], c2 = biasf[2], c3 = biasf[3];
        #pragma unroll
        for (int ks = 0; ks < 4; ++ks) {
            MF(c0, afrX[0][ks], xb[ks]);
            MF(c1, afrX[1][ks], xb[ks]);
            MF(c2, afrX[2][ks], xb[ks]);
            MF(c3, afrX[3][ks], xb[ks]);
        }
        float* wp = &P[0][0] + cr * XPT + bcol * XPB + 16 * w + 4 * quad;
        *(f32x4*)(wp)       = c0;
        *(f32x4*)(wp + 64)  = c1;
        *(f32x4*)(wp + 128) = c2;
        *(f32x4*)(wp + 192) = c3;
    }
    block_sync_lds();       // [B] P[0] visible

    float c = 0.f;
    f32x4 xa0, xa1, xa2, xa3;           // xproj seed for current step
    auto load_xa = [&](const float* Pb, int tt) {
        const float* rp = Pb + tt * XPT + bcol * XPB + 16 * w + 4 * quad;
        xa0 = *(const f32x4*)(rp);
        xa1 = *(const f32x4*)(rp + 64);
        xa2 = *(const f32x4*)(rp + 128);
        xa3 = *(const f32x4*)(rp + 192);
    };
    load_xa(&P[0][0], 0);

    for (int k = 0; k < NTILE; ++k) {
        const int doP = (k + 1 < NTILE);
        const char* XSn = (const char*)&XS[(k + 1) & 1][0][0];
        f32x4 pc0, pc1, pc2, pc3;       // xproj acc for tile k+1, kstep = tt
        #pragma unroll
        for (int tt = 0; tt < TT; ++tt) {
            const int cur = tt & 1;     // s = 4k+tt -> parity = tt&1
            // 1) h-frag reads (the ~120-cyc shadow everything below fills)
            const __fp16* Hc = &H2[cur][bcol][quad * 8];
            f16x8 hb0 = *(const f16x8*)(Hc);
            f16x8 hb1 = *(const f16x8*)(Hc + 32);
            // 2) xproj xb reads for kstep tt (in shadow; lgkm in-order, so
            //    compiler's lgkmcnt(N) still releases hb0 first)
            float4 q0, q1;
            if (doP) {
                const unsigned l0 = rbP + (unsigned)tt * 128u;
                q0 = *(const float4*)(XSn + (l0 ^ xoP));
                q1 = *(const float4*)(XSn + ((l0 + 16u) ^ xoP));
            }
            // 3) stage x for tile k+2 (gll; XS[k&1]'s last reads drained at
            //    end of tile k-1; vmcnt drained at this tile's tt==3)
            if (tt == 0 && k + 2 < NTILE) stage_x(k + 2);
            // 4) recurrence MFMAs, g-gate (a2) first: longest act chain
            f32x4 a0 = xa0, a1 = xa1, a2 = xa2, a3 = xa3;
            MF(a2, afrH[2][0], hb0);
            MF(a0, afrH[0][0], hb0);
            MF(a1, afrH[1][0], hb0);
            MF(a3, afrH[3][0], hb0);
            MF(a2, afrH[2][1], hb1);
            MF(a0, afrH[0][1], hb1);
            MF(a1, afrH[1][1], hb1);
            MF(a3, afrH[3][1], hb1);
            // 5) xproj chunk: kstep tt of tile k+1 (same accumulation order
            //    as the prologue burst -> bit-identical)
            if (doP) {
                if (tt == 0) {
                    pc0 = biasf[0]; pc1 = biasf[1];
                    pc2 = biasf[2]; pc3 = biasf[3];
                }
                f16x8 xbv = pack8n(q0, q1);
                MF(pc0, afrX[0][tt], xbv);
                MF(pc1, afrX[1][tt], xbv);
                MF(pc2, afrX[2][tt], xbv);
                MF(pc3, afrX[3][tt], xbv);
                if (tt == TT - 1) {
                    float* wp = &P[(k + 1) & 1][0] + cr * XPT + bcol * XPB
                                + 16 * w + 4 * quad;
                    *(f32x4*)(wp)       = pc0;
                    *(f32x4*)(wp + 64)  = pc1;
                    *(f32x4*)(wp + 128) = pc2;
                    *(f32x4*)(wp + 192) = pc3;
                }
            }
            // 6) next seed (after P-write: at tt==3 it reads rows this same
            //    wave just wrote -- same-wave LDS is in-order, no barrier)
            if (tt < TT - 1)  load_xa(&P[k & 1][0], tt + 1);
            else if (doP)     load_xa(&P[(k + 1) & 1][0], 0);
            // 7) activation: one unit (u=16w+4quad+cr, batch bcol)
            float Eg = fast_exp2(fminf(a2[cr], 60.f));
            float Ei = fast_exp2(-a0[cr]);
            float Ef = fast_exp2(-a1[cr]);
            float Eo = fast_exp2(-a3[cr]);
            float ig = (Eg - 1.f) * fast_rcp((1.f + Ei) * (1.f + Eg));
            float fv = fast_rcp(1.f + Ef);
            c = fmaf(fv, c, ig);
            float Ec = fast_exp2(fminf(TWOLOG2E * c, 60.f));
            float h  = (Ec - 1.f) * fast_rcp((1.f + Eo) * (1.f + Ec));
            H2[cur ^ 1][bcol][16 * w + 4 * quad + cr] = (__fp16)h;
            // 8) once per tile: drain own glls (~3 steps old, ~0 stall);
            //    next barrier publishes them for tile k+1's xb reads
            if (tt == TT - 1) wave_drain_vm();
            block_sync_lds();
        }
    }
    // final h in H2[0] (s=1023: cur=1, writes buf 0); last barrier done.

    if (tid < 4 * NC) {
        const int bl = tid / NC, cl = tid % NC;
        float acc = b_cls[cl];
        const float* wc = W_cls + cl * NH;
        #pragma unroll 8
        for (int k = 0; k < NH; ++k)
            acc = fmaf(wc[k], (float)H2[0][bl][k], acc);
        out[(4 * bb + bl) * NC + cl] = acc;
    }
}

extern "C" void kernel_launch(void* const* d_in, const int* in_sizes, int n_in,
                              void* d_out, int out_size, void* d_ws, size_t ws_size,
                              hipStream_t stream) {
    const float* x     = (const float*)d_in[0];
    const float* W_ih  = (const float*)d_in[1];
    const float* W_hh  = (const float*)d_in[2];
    const float* b_ih  = (const float*)d_in[3];
    const float* b_hh  = (const float*)d_in[4];
    const float* W_cls = (const float*)d_in[5];
    const float* b_cls = (const float*)d_in[6];
    float* out = (float*)d_out;

    lstm_one<<<NB / 4, 256, 0, stream>>>(x, W_ih, W_hh, b_ih, b_hh,
                                         W_cls, b_cls, out);
}